// Round 10
// baseline (100.223 us; speedup 1.0000x reference)
//
#include <hip/hip_runtime.h>

// Gaussian mixture field evaluation via MFMA:
//   out[m] = sum_n exp2( K*q[m,n] + log2(I_n) ),  K = -0.5*log2(e)
// q = dot(P[m][0..9], C[n][0..9]) with split-f16 (hi/lo) operands:
// products hi*hi + lo*hi + hi*lo -> 30 K-slots.
//
// Round 10: 32x32x16 MFMA, two C-chained per tile (k 0-15, then 16-31).
// One 32x32 tile = 1024 pairs per 2 MFMAs (vs 512 in the 16x16x32 form):
// halves per-pair MFMA/load/glue overhead, which r7/r8/r9 showed is the
// binding cost (~124 cy/iter vs 84 modeled; three different staging
// structures all converged at 43-44 us). Exp count per pair is fixed (one
// v_exp_f32 per point-gaussian pair; 13.65 us floor).
//
// Layouts (32x32x16_f16): A: m=lane&31, k=(lane>>5)*8+j. B: n=lane&31,
// same k mapping. C/D (HW-verified m74/m101): col=lane&31,
// row=(reg&3)+8*(reg>>2)+4*(lane>>5), reg in [0,16).

#define M_POINTS 65536
#define N_GAUSS  4096
#define KNEG     (-0.72134752044448170f)   // -0.5 * log2(e)

typedef _Float16 half8    __attribute__((ext_vector_type(8)));
typedef float    float16v __attribute__((ext_vector_type(16)));

__device__ __forceinline__ float fast_exp2(float x) {
#if defined(__has_builtin)
#if __has_builtin(__builtin_amdgcn_exp2f)
    return __builtin_amdgcn_exp2f(x);   // raw v_exp_f32
#else
    return exp2f(x);
#endif
#else
    return exp2f(x);
#endif
}

// ---------------------------------------------------------------------------
// Kernel 1: per-gaussian coefficients as 32x32x16 B-operand fragments.
// Gaussian tile t = 32 gaussians. k-octet o (0..3) for gaussian col nl is
// stored at bfrag[t*128 + o*32 + nl] (half8). Octets 0,1 = first MFMA
// (k 0-15), octets 2,3 = second (k 16-31). 4096 * 64 B = 256 KiB.
// Also zeroes d_out (atomic partials in kernel 2).
// ---------------------------------------------------------------------------
__global__ __launch_bounds__(256) void precompute_bfrag(
    const float* __restrict__ pos, const float* __restrict__ scl,
    const float* __restrict__ rot, const float* __restrict__ inten,
    half8* __restrict__ bfrag, float4* __restrict__ out_zero)
{
    int n = blockIdx.x * 256 + threadIdx.x;
    if (n >= N_GAUSS) return;

    // zero d_out: 65536 floats = 16384 float4 across 4096 threads
    {
        float4 z = make_float4(0.f, 0.f, 0.f, 0.f);
        out_zero[n]         = z;
        out_zero[n + 4096]  = z;
        out_zero[n + 8192]  = z;
        out_zero[n + 12288] = z;
    }

    float qw = rot[4*n+0], qx = rot[4*n+1], qy = rot[4*n+2], qz = rot[4*n+3];
    float nrm = sqrtf(qw*qw + qx*qx + qy*qy + qz*qz) + 1e-8f;
    float ir = 1.0f / nrm;
    qw *= ir; qx *= ir; qy *= ir; qz *= ir;

    float r00 = 1.f - 2.f*(qy*qy + qz*qz);
    float r01 = 2.f*(qx*qy - qz*qw);
    float r02 = 2.f*(qx*qz + qy*qw);
    float r10 = 2.f*(qx*qy + qz*qw);
    float r11 = 1.f - 2.f*(qx*qx + qz*qz);
    float r12 = 2.f*(qy*qz - qx*qw);
    float r20 = 2.f*(qx*qz - qy*qw);
    float r21 = 2.f*(qy*qz + qx*qw);
    float r22 = 1.f - 2.f*(qx*qx + qy*qy);

    float s0 = fabsf(scl[3*n+0]) + 1e-6f;
    float s1 = fabsf(scl[3*n+1]) + 1e-6f;
    float s2 = fabsf(scl[3*n+2]) + 1e-6f;
    float w0 = 1.f/(s0*s0), w1 = 1.f/(s1*s1), w2 = 1.f/(s2*s2);

    float a00 = r00*r00*w0 + r01*r01*w1 + r02*r02*w2;
    float a01 = r00*r10*w0 + r01*r11*w1 + r02*r12*w2;
    float a02 = r00*r20*w0 + r01*r21*w1 + r02*r22*w2;
    float a11 = r10*r10*w0 + r11*r11*w1 + r12*r12*w2;
    float a12 = r10*r20*w0 + r11*r21*w1 + r12*r22*w2;
    float a22 = r20*r20*w0 + r21*r21*w1 + r22*r22*w2;

    float p0 = pos[3*n+0], p1 = pos[3*n+1], p2 = pos[3*n+2];
    float b0 = a00*p0 + a01*p1 + a02*p2;
    float b1 = a01*p0 + a11*p1 + a12*p2;
    float b2 = a02*p0 + a12*p1 + a22*p2;
    float c  = b0*p0 + b1*p1 + b2*p2;

    float I = fmaxf(inten[n], 1e-30f);   // I=0 -> t very negative -> exp2 -> 0

    float C[10];
    C[0] = KNEG * a00;       C[1] = KNEG * a11;       C[2] = KNEG * a22;
    C[3] = 2.f*KNEG * a01;   C[4] = 2.f*KNEG * a02;   C[5] = 2.f*KNEG * a12;
    C[6] = -2.f*KNEG * b0;   C[7] = -2.f*KNEG * b1;   C[8] = -2.f*KNEG * b2;
    C[9] = KNEG * c + log2f(I);

    _Float16 chi[10], clo[10];
#pragma unroll
    for (int j = 0; j < 10; ++j) {
        chi[j] = (_Float16)C[j];
        clo[j] = (_Float16)(C[j] - (float)chi[j]);
    }

    const int tile = n >> 5, nl = n & 31;
#pragma unroll
    for (int o = 0; o < 4; ++o) {
        half8 v;
#pragma unroll
        for (int j = 0; j < 8; ++j) {
            const int k = o*8 + j;
            _Float16 h = (_Float16)0.f;
            if (k < 30) {
                const int jm = k / 3, s = k % 3;
                h = (s == 2) ? clo[jm] : chi[jm];
            }
            v[j] = h;
        }
        bfrag[tile*128 + o*32 + nl] = v;
    }
}

// ---------------------------------------------------------------------------
// A-frag octet builder: named scalars + first-class vectors (SROA-proof).
// k-slot layout: k=3j -> phi_j, 3j+1 -> plo_j, 3j+2 -> phi_j; k=30,31 -> 0.
// Octet o holds k = o*8 .. o*8+7. (Same slots as the 16x16 version.)
// ---------------------------------------------------------------------------
__device__ __forceinline__ half8 build_afrag(float x, float y, float z, int o) {
    const float P0 = x*x, P1 = y*y, P2 = z*z;
    const float P3 = x*y, P4 = x*z, P5 = y*z;

    _Float16 h0 = (_Float16)P0, l0 = (_Float16)(P0 - (float)h0);
    _Float16 h1 = (_Float16)P1, l1 = (_Float16)(P1 - (float)h1);
    _Float16 h2 = (_Float16)P2, l2 = (_Float16)(P2 - (float)h2);
    _Float16 h3 = (_Float16)P3, l3 = (_Float16)(P3 - (float)h3);
    _Float16 h4 = (_Float16)P4, l4 = (_Float16)(P4 - (float)h4);
    _Float16 h5 = (_Float16)P5, l5 = (_Float16)(P5 - (float)h5);
    _Float16 h6 = (_Float16)x,  l6 = (_Float16)(x - (float)h6);
    _Float16 h7 = (_Float16)y,  l7 = (_Float16)(y - (float)h7);
    _Float16 h8 = (_Float16)z,  l8 = (_Float16)(z - (float)h8);
    const _Float16 one = (_Float16)1.f, zer = (_Float16)0.f;

    // k:       0   1   2   3   4   5   6   7
    half8 c0 = {h0, l0, h0, h1, l1, h1, h2, l2};
    // k:       8   9  10  11  12  13  14  15
    half8 c1 = {h2, h3, l3, h3, h4, l4, h4, h5};
    // k:      16  17  18  19  20  21  22  23
    half8 c2 = {l5, h5, h6, l6, h6, h7, l7, h7};
    // k:      24  25  26  27  28  29  30  31
    half8 c3 = {h8, l8, h8, one, zer, one, zer, zer};

    return (o == 0) ? c0 : (o == 1) ? c1 : (o == 2) ? c2 : c3;
}

// ---------------------------------------------------------------------------
// Kernel 2: main evaluation, 32x32 tiles. grid(512, 4) x 256 threads
// (4 waves/block, 8 blocks/CU). Each wave owns one 32-point tile and sweeps
// 32 gaussian 32-tiles straight from L2-resident bfrag. Per iteration:
// 2 loads + 2 chained MFMAs -> 1024 pairs -> 16 exps + 8 pk_adds.
// Epilogue: 5-step butterfly over the 32 gaussian cols, atomicAdd
// (4 partials per output element).
// ---------------------------------------------------------------------------
#define PT_BLOCKS 512               // 65536 / (32 pts * 4 waves)
#define G_SPLIT   4
#define NT        (128 / G_SPLIT)   // 32 gaussian tiles per wave sweep

__global__ __launch_bounds__(256) void gauss_eval(
    const float* __restrict__ pts,
    const half8* __restrict__ bfrag,
    float* __restrict__ out)
{
    const int tid  = threadIdx.x;
    const int lane = tid & 63;
    const int wv   = tid >> 6;
    const int nl   = lane & 31;          // A row m / B col n / D col
    const int h    = lane >> 5;          // k-octet group / D row offset

    const int pbase = (blockIdx.x * 4 + wv) * 32;   // this wave's 32 points
    const int pt = pbase + nl;
    const float x = pts[3*pt+0], y = pts[3*pt+1], z = pts[3*pt+2];

    const half8 af1 = build_afrag(x, y, z, h);       // k 0-15
    const half8 af2 = build_afrag(x, y, z, 2 + h);   // k 16-31

    float16v acc = {0.f,0.f,0.f,0.f,0.f,0.f,0.f,0.f,
                    0.f,0.f,0.f,0.f,0.f,0.f,0.f,0.f};
    const float16v zero16 = {0.f,0.f,0.f,0.f,0.f,0.f,0.f,0.f,
                             0.f,0.f,0.f,0.f,0.f,0.f,0.f,0.f};

    // this wave's B stream: NT tiles, 2 KiB each, L2-hot
    const half8* src = bfrag + (blockIdx.y * NT) * 128 + lane;

#pragma unroll 2
    for (int i = 0; i < NT; ++i) {
        half8 b1 = src[i*128];        // k-octets 0,1
        half8 b2 = src[i*128 + 64];   // k-octets 2,3
        float16v d = __builtin_amdgcn_mfma_f32_32x32x16_f16(af1, b1, zero16, 0, 0, 0);
        d = __builtin_amdgcn_mfma_f32_32x32x16_f16(af2, b2, d, 0, 0, 0);
        float16v e;
#pragma unroll
        for (int r = 0; r < 16; ++r) e[r] = fast_exp2(d[r]);
        acc += e;                     // 8 x v_pk_add_f32
    }

    // butterfly-reduce over the 32 gaussian columns (lanes within each half)
#pragma unroll
    for (int m = 1; m <= 16; m <<= 1) {
        float16v t;
#pragma unroll
        for (int r = 0; r < 16; ++r) t[r] = __shfl_xor(acc[r], m);
        acc += t;
    }

    // lane nl==0 of each half h holds 16 row-sums:
    // row = (r&3) + 8*(r>>2) + 4*h
    if (nl == 0) {
#pragma unroll
        for (int r = 0; r < 16; ++r) {
            const int row = (r & 3) + 8 * (r >> 2) + 4 * h;
            atomicAdd(&out[pbase + row], acc[r]);
        }
    }
}

extern "C" void kernel_launch(void* const* d_in, const int* in_sizes, int n_in,
                              void* d_out, int out_size, void* d_ws, size_t ws_size,
                              hipStream_t stream) {
    const float* sample_points = (const float*)d_in[0];
    const float* positions     = (const float*)d_in[1];
    const float* scales        = (const float*)d_in[2];
    const float* rotations     = (const float*)d_in[3];
    const float* intensities   = (const float*)d_in[4];

    half8* bfrag = (half8*)d_ws;   // 256 KiB

    precompute_bfrag<<<N_GAUSS / 256, 256, 0, stream>>>(
        positions, scales, rotations, intensities, bfrag, (float4*)d_out);

    gauss_eval<<<dim3(PT_BLOCKS, G_SPLIT), 256, 0, stream>>>(
        sample_points, bfrag, (float*)d_out);
}